// Round 18
// baseline (139.935 us; speedup 1.0000x reference)
//
#include <hip/hip_runtime.h>
#include <math.h>

#define N_NODES 100000
#define N_EDGES 1600000
#define NFEAT   256
#define NHID    128
#define NHID2   64
#define NCLASS  40
#define NCLS_P  64

typedef __attribute__((ext_vector_type(8))) short bf16x8;
typedef __attribute__((ext_vector_type(4))) float f32x4;
typedef __attribute__((ext_vector_type(2))) float f32x2;

typedef __attribute__((address_space(1))) const void gas_void;
typedef __attribute__((address_space(3))) void las_void;

static __device__ inline unsigned short f2bf(float f) {
    union { float f; unsigned u; } v; v.f = f;
    unsigned r = v.u + 0x7FFF + ((v.u >> 16) & 1);   // RNE
    return (unsigned short)(r >> 16);
}
static __device__ inline unsigned pkbf(float a, float b) {   // packed bf16x2
    return (unsigned)f2bf(a) | ((unsigned)f2bf(b) << 16);
}
static __device__ inline float bfl(unsigned u) {             // low bf16 -> f32
    union { unsigned u; float f; } v; v.u = u << 16; return v.f;
}
static __device__ inline float bfraw(unsigned u) {           // high bf16 -> f32 (low mantissa garbage)
    union { unsigned u; float f; } v; v.u = u; return v.f;
}

// ---- fp8 e4m3 pack/unpack: HW cvt if available, bitwise fallback ----------
#if __has_builtin(__builtin_amdgcn_cvt_pk_fp8_f32) && __has_builtin(__builtin_amdgcn_cvt_pk_f32_fp8)
#define FP8_HW 1
#else
#define FP8_HW 0
static __device__ inline unsigned f2fp8_sw(float f) {        // e4m3fn, RNE, FTZ below 2^-6
    union { float f; unsigned u; } v; v.f = f;
    unsigned s = (v.u >> 24) & 0x80u;
    int e = (int)((v.u >> 23) & 0xFF) - 120;                 // fp8 exp field
    unsigned m = v.u & 0x7FFFFFu;
    if (e < 1) return s;                                     // flush tiny to 0
    unsigned keep = m >> 20, rest = m & 0xFFFFFu;
    keep += (rest > 0x80000u) || (rest == 0x80000u && (keep & 1));
    if (keep == 8) { keep = 0; ++e; }
    if (e > 15) { e = 15; keep = 6; }                        // clamp to 448
    return s | ((unsigned)e << 3) | keep;
}
static __device__ inline float fp8f_sw(unsigned b) {
    unsigned e = (b >> 3) & 0xF;
    union { unsigned u; float f; } v;
    v.u = ((b & 0x80u) << 24) | ((e + 120) << 23) | ((b & 7u) << 20);
    return e ? v.f : 0.f;
}
#endif

static __device__ inline unsigned pack4_fp8(float a, float b, float c, float d) {
#if FP8_HW
    int r = __builtin_amdgcn_cvt_pk_fp8_f32(a, b, 0, false);
    r = __builtin_amdgcn_cvt_pk_fp8_f32(c, d, r, true);
    return (unsigned)r;
#else
    return f2fp8_sw(a) | (f2fp8_sw(b) << 8) | (f2fp8_sw(c) << 16) | (f2fp8_sw(d) << 24);
#endif
}
static __device__ inline void unpack4_fp8(unsigned g, f32x2& lo, f32x2& hi) {
#if FP8_HW
    lo = __builtin_amdgcn_cvt_pk_f32_fp8((int)g, false);
    hi = __builtin_amdgcn_cvt_pk_f32_fp8((int)g, true);
#else
    lo.x = fp8f_sw(g & 0xFF); lo.y = fp8f_sw((g >> 8) & 0xFF);
    hi.x = fp8f_sw((g >> 16) & 0xFF); hi.y = fp8f_sw(g >> 24);
#endif
}

// ---------------------------------------------------------------------------
// Merged prep: CSR row_ptr + 3 weight transposes + packed edge meta {col,val}.
// ---------------------------------------------------------------------------
#define PREP_T0 (N_NODES + 1)
#define PREP_T1 (PREP_T0 + NHID * NFEAT)
#define PREP_T2 (PREP_T1 + NHID2 * NHID)
#define PREP_T3 (PREP_T2 + NCLS_P * 192)
#define PREP_T4 (PREP_T3 + N_EDGES)
__global__ void prep(const int* __restrict__ er, int* __restrict__ row_ptr,
                     const float* __restrict__ w1, unsigned short* __restrict__ w1t,
                     const float* __restrict__ w2, unsigned short* __restrict__ w2t,
                     const float* __restrict__ wl, unsigned short* __restrict__ wlt,
                     const int* __restrict__ ec, const float* __restrict__ ev,
                     uint2* __restrict__ meta) {
    int idx = blockIdx.x * blockDim.x + threadIdx.x;
    if (idx < PREP_T0) {
        int lo = 0, hi = N_EDGES;
        while (lo < hi) { int mid = (lo + hi) >> 1; if (er[mid] < idx) lo = mid + 1; else hi = mid; }
        row_ptr[idx] = lo;
    } else if (idx < PREP_T1) {
        int i = idx - PREP_T0;          // w1t[n][k]: n<128, k<256
        int n = i >> 8, k = i & 255;
        w1t[i] = f2bf(w1[k * NHID + n]);
    } else if (idx < PREP_T2) {
        int i = idx - PREP_T1;          // w2t[n][k]: n<64, k<128
        int n = i >> 7, k = i & 127;
        w2t[i] = f2bf(w2[k * NHID2 + n]);
    } else if (idx < PREP_T3) {
        int i = idx - PREP_T2;          // wlt[n][k]: n<64 (pad>=40 -> 0), k<192
        int n = i / 192, k = i - n * 192;
        wlt[i] = (n < NCLASS) ? f2bf(wl[k * NCLASS + n]) : (unsigned short)0;
    } else if (idx < PREP_T4) {
        int i = idx - PREP_T3;
        uint2 m; m.x = (unsigned)ec[i];
        union { float f; unsigned u; } v; v.f = ev[i];
        m.y = v.u;
        meta[i] = m;
    }
}

// ---------------------------------------------------------------------------
// Layer-1 GEMM, DMA-staged A: sup8[M][128](fp8) = fp8( x[M][256](f32) @ w1t^T )
// A panel DMA'd into LDS as RAW F32 via global_load_lds (16B/lane, one instr
// per row, no VGPR round-trip, no staging converts). One vmcnt drain at the
// single barrier. f32->bf16 conversion happens at fragment build (2 x
// ds_read_b128 + 4 v_cvt_pk per frag, co-issues with MFMA).
// B (w1t, 64KB, L2-hot) in registers per wave (R16 scheme).
// LDS: Asf[64][260] f32 = 66.6KB -> 2 blocks/CU. Row stride 260 dw == 4
// (mod 32) -> fragment reads 2-way bank aliasing (free).
// Epilogue: acc -> f32 LDS repack (reuse Asf) -> 32B/thread fp8 stores.
// ---------------------------------------------------------------------------
__global__ __launch_bounds__(256) void gemm1_glds(const float* __restrict__ A,
                                                  const unsigned short* __restrict__ Bt,
                                                  unsigned char* __restrict__ C, int M) {
    const int K = 256, SF = 260;                    // f32 row stride (pad 4)
    extern __shared__ char smem[];
    float* Asf = (float*)smem;                      // [64][260] f32

    int tid = threadIdx.x;
    int lane = tid & 63, wid = tid >> 6;            // wave = col-slice owner
    int wc = wid;
    int row0 = blockIdx.x * 64;

    // ---- B slice -> registers (16 frags; L2-resident w1t)
    bf16x8 br[2][8];
    #pragma unroll
    for (int ni = 0; ni < 2; ++ni)
        #pragma unroll
        for (int t = 0; t < 8; ++t) {
            int n = wc * 32 + ni * 16 + (lane & 15);
            br[ni][t] = *(const bf16x8*)(Bt + (size_t)n * K + t * 32 + ((lane >> 4) << 3));
        }

    // ---- DMA A panel: wave wid stages rows wid*16 .. wid*16+15.
    // One global_load_lds per row: 64 lanes x 16B = 1024B = full 256-f32 row.
    #pragma unroll
    for (int r = 0; r < 16; ++r) {
        int lrow = wid * 16 + r;
        int grow = row0 + lrow;
        if (grow >= M) grow = M - 1;                // clamp; garbage rows never stored
        const float* src = A + (size_t)grow * K + lane * 4;
        float* dst = &Asf[lrow * SF];               // wave-uniform base; lane x 16B
        __builtin_amdgcn_global_load_lds((gas_void*)src, (las_void*)dst, 16, 0, 0);
    }
    __syncthreads();                                // single drain

    // ---- barrier-free MFMA loop: frag build converts f32->bf16 in-register
    f32x4 acc[4][2];
    #pragma unroll
    for (int i = 0; i < 4; ++i)
        #pragma unroll
        for (int j = 0; j < 2; ++j) acc[i][j] = f32x4{0.f, 0.f, 0.f, 0.f};

    #pragma unroll
    for (int t = 0; t < 8; ++t) {
        bf16x8 af[4];
        #pragma unroll
        for (int mi = 0; mi < 4; ++mi) {
            const float* rp = &Asf[(mi * 16 + (lane & 15)) * SF + t * 32 + ((lane >> 4) << 3)];
            f32x4 lo = *(const f32x4*)rp;
            f32x4 hi = *(const f32x4*)(rp + 4);
            union { unsigned u[4]; bf16x8 v; } cv;
            cv.u[0] = pkbf(lo[0], lo[1]); cv.u[1] = pkbf(lo[2], lo[3]);
            cv.u[2] = pkbf(hi[0], hi[1]); cv.u[3] = pkbf(hi[2], hi[3]);
            af[mi] = cv.v;
        }
        #pragma unroll
        for (int mi = 0; mi < 4; ++mi)
            #pragma unroll
            for (int ni = 0; ni < 2; ++ni)
                acc[mi][ni] = __builtin_amdgcn_mfma_f32_16x16x32_bf16(af[mi], br[ni][t], acc[mi][ni], 0, 0, 0);
    }

    // ---- fp8 packed epilogue via LDS repack (reuse Asf; 64*132*4 = 33792 B)
    __syncthreads();
    float* Lf = Asf; const int LS = 132;
    #pragma unroll
    for (int mi = 0; mi < 4; ++mi) {
        int rt = mi * 16 + ((lane >> 4) << 2);
        #pragma unroll
        for (int ni = 0; ni < 2; ++ni) {
            int ct = wc * 32 + ni * 16 + (lane & 15);
            #pragma unroll
            for (int r = 0; r < 4; ++r) Lf[(rt + r) * LS + ct] = acc[mi][ni][r];
        }
    }
    __syncthreads();
    int rl = tid >> 2, c0 = (tid & 3) * 32;
    int row = row0 + rl;
    if (row < M) {
        unsigned u[8];
        #pragma unroll
        for (int q = 0; q < 8; ++q) {
            f32x4 v = *(const f32x4*)&Lf[rl * LS + c0 + q * 4];
            u[q] = pack4_fp8(v[0], v[1], v[2], v[3]);
        }
        unsigned char* o = C + (size_t)row * 128 + c0;
        *(uint4*)o = uint4{u[0], u[1], u[2], u[3]};
        *(uint4*)(o + 16) = uint4{u[4], u[5], u[6], u[7]};
    }
}

// ---------------------------------------------------------------------------
// Single-phase full-K MFMA GEMM (layer 2): C = A @ Bt^T.
// CMODE 1: bf16 strided stores. CMODE 2 (BN=64): fp8 packed via LDS repack.
// ---------------------------------------------------------------------------
template <int BN, int K, int CMODE>
__global__ __launch_bounds__(512) void gemm_full(const unsigned short* __restrict__ A,
                                                 const unsigned short* __restrict__ Bt,
                                                 void* __restrict__ C,
                                                 int M, int lda, int ldc) {
    const int S   = K + 8;
    const int OCT = K / 8;
    const int WC  = (BN == 128) ? 4 : 2;
    const int MF  = (BN == 128) ? 4 : 2;
    const int NF  = 2;
    const int NT  = K / 32;

    extern __shared__ char smem[];
    unsigned short* As = (unsigned short*)smem;           // [128][S]
    unsigned short* Bs = As + 128 * S;                    // [BN][S]

    int tid = threadIdx.x;
    int lane = tid & 63, wid = tid >> 6;
    int wr = wid / WC, wc = wid % WC;
    int row0 = blockIdx.x * 128;

    {
        const int NI = 128 * OCT / 512;
        uint4 av[NI];
        #pragma unroll
        for (int i = 0; i < NI; ++i) {
            int s = tid + i * 512;
            int m = s / OCT, kk = (s - m * OCT) * 8;
            int row = row0 + m;
            av[i] = (row < M) ? *(const uint4*)(A + (size_t)row * lda + kk)
                              : uint4{0u, 0u, 0u, 0u};
        }
        #pragma unroll
        for (int i = 0; i < NI; ++i) {
            int s = tid + i * 512;
            int m = s / OCT, kk = (s - m * OCT) * 8;
            *(uint4*)&As[m * S + kk] = av[i];
        }
    }
    {
        const int NI = BN * OCT / 512;
        uint4 bv[NI];
        #pragma unroll
        for (int i = 0; i < NI; ++i) {
            int s = tid + i * 512;
            int n = s / OCT, kk = (s - n * OCT) * 8;
            bv[i] = *(const uint4*)(Bt + (size_t)n * K + kk);
        }
        #pragma unroll
        for (int i = 0; i < NI; ++i) {
            int s = tid + i * 512;
            int n = s / OCT, kk = (s - n * OCT) * 8;
            *(uint4*)&Bs[n * S + kk] = bv[i];
        }
    }
    __syncthreads();

    f32x4 acc[MF][NF];
    #pragma unroll
    for (int i = 0; i < MF; ++i)
        #pragma unroll
        for (int j = 0; j < NF; ++j) acc[i][j] = f32x4{0.f, 0.f, 0.f, 0.f};

    #pragma unroll
    for (int t = 0; t < NT; ++t) {
        bf16x8 af[MF], bfr[NF];
        #pragma unroll
        for (int mi = 0; mi < MF; ++mi)
            af[mi] = *(const bf16x8*)&As[(wr * (MF * 16) + mi * 16 + (lane & 15)) * S + t * 32 + (lane >> 4) * 8];
        #pragma unroll
        for (int ni = 0; ni < NF; ++ni)
            bfr[ni] = *(const bf16x8*)&Bs[(wc * (NF * 16) + ni * 16 + (lane & 15)) * S + t * 32 + (lane >> 4) * 8];
        #pragma unroll
        for (int mi = 0; mi < MF; ++mi)
            #pragma unroll
            for (int ni = 0; ni < NF; ++ni)
                acc[mi][ni] = __builtin_amdgcn_mfma_f32_16x16x32_bf16(af[mi], bfr[ni], acc[mi][ni], 0, 0, 0);
    }

    if (CMODE == 1) {
        #pragma unroll
        for (int mi = 0; mi < MF; ++mi) {
            int rbase = row0 + wr * (MF * 16) + mi * 16 + ((lane >> 4) << 2);
            #pragma unroll
            for (int ni = 0; ni < NF; ++ni) {
                int col = wc * (NF * 16) + ni * 16 + (lane & 15);
                #pragma unroll
                for (int r = 0; r < 4; ++r) {
                    int row = rbase + r;
                    if (row < M) ((unsigned short*)C)[(size_t)row * ldc + col] = f2bf(acc[mi][ni][r]);
                }
            }
        }
    } else {
        __syncthreads();
        float* Lf = (float*)As; const int LS = BN + 4;         // 68
        #pragma unroll
        for (int mi = 0; mi < MF; ++mi) {
            int rt = wr * (MF * 16) + mi * 16 + ((lane >> 4) << 2);
            #pragma unroll
            for (int ni = 0; ni < NF; ++ni) {
                int ct = wc * (NF * 16) + ni * 16 + (lane & 15);
                #pragma unroll
                for (int r = 0; r < 4; ++r) Lf[(rt + r) * LS + ct] = acc[mi][ni][r];
            }
        }
        __syncthreads();
        int rl = tid >> 2, c0 = (tid & 3) * 16;
        int row = row0 + rl;
        if (row < M) {
            unsigned u[4];
            #pragma unroll
            for (int q = 0; q < 4; ++q) {
                f32x4 v = *(const f32x4*)&Lf[rl * LS + c0 + q * 4];
                u[q] = pack4_fp8(v[0], v[1], v[2], v[3]);
            }
            *(uint4*)((unsigned char*)C + (size_t)row * BN + c0) = uint4{u[0], u[1], u[2], u[3]};
        }
    }
}

// ---------------------------------------------------------------------------
// Layer-1 SpMM over fp8 sup8[node][128] (128B/row) + bias + relu -> bf16 out.
// ---------------------------------------------------------------------------
__global__ __launch_bounds__(256) void spmm_fp8(const unsigned char* __restrict__ sup8,
                                                const int* __restrict__ row_ptr,
                                                const uint2* __restrict__ meta,
                                                const float* __restrict__ bias,
                                                unsigned short* __restrict__ out,
                                                int out_stride, int n_nodes) {
    __shared__ uint2 mlds[4][64];

    int wave = threadIdx.x >> 6;
    int lane = threadIdx.x & 63;
    int node = blockIdx.x * 4 + wave;
    if (node >= n_nodes) return;

    int sub = lane >> 5, l = lane & 31;
    int e0 = row_ptr[node];
    int cnt = row_ptr[node + 1] - e0;
    unsigned loff = (unsigned)(l << 2);

    f32x2 a0 = {0.f, 0.f}, a1 = {0.f, 0.f};

    for (int o = 0; o < cnt; o += 64) {
        int rem = min(64, cnt - o);
        uint2 m;
        if (lane < rem) m = meta[e0 + o + lane];
        else { m.x = 0u; m.y = 0u; }
        mlds[wave][lane] = m;

        for (int j = 0; j < rem; j += 16) {
            unsigned g[8]; float vv[8];
            #pragma unroll
            for (int t = 0; t < 8; ++t) {
                uint2 cm = mlds[wave][j + 2 * t + sub];
                g[t] = *(const unsigned*)(sup8 + (((size_t)cm.x) << 7) + loff);
                union { unsigned u; float f; } c; c.u = cm.y;
                vv[t] = c.f;
            }
            #pragma unroll
            for (int t = 0; t < 8; ++t) {
                f32x2 lo, hi;
                unpack4_fp8(g[t], lo, hi);
                f32x2 v2 = {vv[t], vv[t]};
                a0 += v2 * lo;
                a1 += v2 * hi;
            }
        }
    }

    a0.x += __shfl_xor(a0.x, 32); a0.y += __shfl_xor(a0.y, 32);
    a1.x += __shfl_xor(a1.x, 32); a1.y += __shfl_xor(a1.y, 32);

    if (lane < 32) {
        float4 bv = *(const float4*)(bias + 4 * l);
        float r0 = a0.x + bv.x, r1 = a0.y + bv.y;
        float r2 = a1.x + bv.z, r3 = a1.y + bv.w;
        r0 = r0 > 0.f ? r0 : 0.f; r1 = r1 > 0.f ? r1 : 0.f;
        r2 = r2 > 0.f ? r2 : 0.f; r3 = r3 > 0.f ? r3 : 0.f;
        uint2 pk; pk.x = pkbf(r0, r1); pk.y = pkbf(r2, r3);
        *(uint2*)(out + (size_t)node * out_stride + 4 * l) = pk;
    }
}

// ---------------------------------------------------------------------------
// Layer-2 SpMM over fp8 sup8_2[node][64] (64B/row) + bias + relu -> bf16 out.
// ---------------------------------------------------------------------------
__global__ __launch_bounds__(256) void spmm2_fp8(const unsigned char* __restrict__ sup8,
                                                 const int* __restrict__ row_ptr,
                                                 const uint2* __restrict__ meta,
                                                 const float* __restrict__ bias,
                                                 unsigned short* __restrict__ out,
                                                 int out_stride, int n_nodes) {
    __shared__ uint2 mlds[4][64];

    int wave = threadIdx.x >> 6;
    int lane = threadIdx.x & 63;
    int node = blockIdx.x * 4 + wave;
    if (node >= n_nodes) return;

    int sub = lane >> 4, l = lane & 15;
    int e0 = row_ptr[node];
    int cnt = row_ptr[node + 1] - e0;
    unsigned loff = (unsigned)(l << 2);

    f32x2 a0 = {0.f, 0.f}, a1 = {0.f, 0.f};

    for (int o = 0; o < cnt; o += 64) {
        int rem = min(64, cnt - o);
        uint2 m;
        if (lane < rem) m = meta[e0 + o + lane];
        else { m.x = 0u; m.y = 0u; }
        mlds[wave][lane] = m;

        for (int j = 0; j < rem; j += 32) {
            unsigned g[8]; float vv[8];
            #pragma unroll
            for (int t = 0; t < 8; ++t) {
                uint2 cm = mlds[wave][j + 4 * t + sub];
                g[t] = *(const unsigned*)(sup8 + (((size_t)cm.x) << 6) + loff);
                union { unsigned u; float f; } c; c.u = cm.y;
                vv[t] = c.f;
            }
            #pragma unroll
            for (int t = 0; t < 8; ++t) {
                f32x2 lo, hi;
                unpack4_fp8(g[t], lo, hi);
                f32x2 v2 = {vv[t], vv[t]};
                a0 += v2 * lo;
                a1 += v2 * hi;
            }
        }
    }

    a0.x += __shfl_xor(a0.x, 32); a0.y += __shfl_xor(a0.y, 32);
    a1.x += __shfl_xor(a1.x, 32); a1.y += __shfl_xor(a1.y, 32);
    a0.x += __shfl_xor(a0.x, 16); a0.y += __shfl_xor(a0.y, 16);
    a1.x += __shfl_xor(a1.x, 16); a1.y += __shfl_xor(a1.y, 16);

    if (lane < 16) {
        float4 bv = *(const float4*)(bias + 4 * l);
        float r0 = a0.x + bv.x, r1 = a0.y + bv.y;
        float r2 = a1.x + bv.z, r3 = a1.y + bv.w;
        r0 = r0 > 0.f ? r0 : 0.f; r1 = r1 > 0.f ? r1 : 0.f;
        r2 = r2 > 0.f ? r2 : 0.f; r3 = r3 > 0.f ? r3 : 0.f;
        uint2 pk; pk.x = pkbf(r0, r1); pk.y = pkbf(r2, r3);
        *(uint2*)(out + (size_t)node * out_stride + 4 * l) = pk;
    }
}

// ---------------------------------------------------------------------------
// Fused head: out = log_softmax(x_cat[M,192](bf16) @ wlt[64,192]^T + bl).
// ---------------------------------------------------------------------------
__global__ __launch_bounds__(512) void head_fused(const unsigned short* __restrict__ A,
                                                  const unsigned short* __restrict__ Bt,
                                                  const float* __restrict__ bl,
                                                  float* __restrict__ out, int M) {
    const int K = 192, S = K + 8, OCT = K / 8;   // 24
    const int MF = 2, NF = 2, NT = 6;

    extern __shared__ char smem[];
    unsigned short* As = (unsigned short*)smem;        // [128][200]
    unsigned short* Bs = As + 128 * S;                 // [64][200]
    float* L  = (float*)(Bs + 64 * S);                 // [128][65]
    float* bls = L + 128 * 65;                         // [40]

    int tid = threadIdx.x;
    int lane = tid & 63, wid = tid >> 6;
    int wr = wid >> 1, wc = wid & 1;
    int row0 = blockIdx.x * 128;
    if (tid < NCLASS) bls[tid] = bl[tid];

    {
        uint4 av[6];
        #pragma unroll
        for (int i = 0; i < 6; ++i) {
            int s = tid + i * 512;
            int m = s / OCT, kk = (s - m * OCT) * 8;
            int row = row0 + m;
            av[i] = (row < M) ? *(const uint4*)(A + (size_t)row * 192 + kk)
                              : uint4{0u, 0u, 0u, 0u};
        }
        #pragma unroll
        for (int i = 0; i < 6; ++i) {
            int s = tid + i * 512;
            int m = s / OCT, kk = (s - m * OCT) * 8;
            *(uint4*)&As[m * S + kk] = av[i];
        }
    }
    {
        uint4 bv[3];
        #pragma unroll
        for (int i = 0; i < 3; ++i) {
            int s = tid + i * 512;
            int n = s / OCT, kk = (s - n * OCT) * 8;
            bv[i] = *(const uint4*)(Bt + (size_t)n * 192 + kk);
        }
        #pragma unroll
        for (int i = 0; i < 3; ++i) {
            int s = tid + i * 512;
            int n = s / OCT, kk = (s - n * OCT) * 8;
            *(uint4*)&Bs[n * S + kk] = bv[i];
        }
    }
    __syncthreads();

    f32x4 acc[MF][NF];
    #pragma unroll
    for (int i = 0; i < MF; ++i)
        #pragma unroll
        for (int j = 0; j < NF; ++j) acc[i][j] = f32x4{0.f, 0.f, 0.f, 0.f};

    #pragma unroll
    for (int t = 0; t < NT; ++t) {
        bf16x8 af[MF], bfr[NF];
        #pragma unroll
        for (int mi = 0; mi < MF; ++mi)
            af[mi] = *(const bf16x8*)&As[(wr * 32 + mi * 16 + (lane & 15)) * S + t * 32 + (lane >> 4) * 8];
        #pragma unroll
        for (int ni = 0; ni < NF; ++ni)
            bfr[ni] = *(const bf16x8*)&Bs[(wc * 32 + ni * 16 + (lane & 15)) * S + t * 32 + (lane >> 4) * 8];
        #pragma unroll
        for (int mi = 0; mi < MF; ++mi)
            #pragma unroll
            for (int ni = 0; ni < NF; ++ni)
                acc[mi][ni] = __builtin_amdgcn_mfma_f32_16x16x32_bf16(af[mi], bfr[ni], acc[mi][ni], 0, 0, 0);
    }

    #pragma unroll
    for (int mi = 0; mi < MF; ++mi) {
        int rt = wr * 32 + mi * 16 + ((lane >> 4) << 2);
        #pragma unroll
        for (int ni = 0; ni < NF; ++ni) {
            int ct = wc * 32 + ni * 16 + (lane & 15);
            #pragma unroll
            for (int r = 0; r < 4; ++r) L[(rt + r) * 65 + ct] = acc[mi][ni][r];
        }
    }
    __syncthreads();

    {
        int r = tid >> 2, h = tid & 3;
        int row = row0 + r;
        if (row < M) {
            float vals[10];
            float m = -1e30f;
            #pragma unroll
            for (int c = 0; c < 10; ++c) {
                float tv = L[r * 65 + h * 10 + c] + bls[h * 10 + c];
                vals[c] = tv;
                m = fmaxf(m, tv);
            }
            m = fmaxf(m, __shfl_xor(m, 1));
            m = fmaxf(m, __shfl_xor(m, 2));
            float s = 0.f;
            #pragma unroll
            for (int c = 0; c < 10; ++c) s += __expf(vals[c] - m);
            s += __shfl_xor(s, 1);
            s += __shfl_xor(s, 2);
            float lg = __logf(s);
            float* o = out + (size_t)row * NCLASS + h * 10;
            #pragma unroll
            for (int c = 0; c < 10; ++c) o[c] = vals[c] - m - lg;
        }
    }
}

// ---------------------------------------------------------------------------
extern "C" void kernel_launch(void* const* d_in, const int* in_sizes, int n_in,
                              void* d_out, int out_size, void* d_ws, size_t ws_size,
                              hipStream_t stream) {
    const float* x        = (const float*)d_in[0];
    const int*   edge_row = (const int*)d_in[1];
    const int*   edge_col = (const int*)d_in[2];
    const float* edge_val = (const float*)d_in[3];
    const float* w1       = (const float*)d_in[4];
    const float* b1       = (const float*)d_in[5];
    const float* w2       = (const float*)d_in[6];
    const float* b2       = (const float*)d_in[7];
    const float* wl       = (const float*)d_in[8];
    const float* bl       = (const float*)d_in[9];
    float* out = (float*)d_out;
    (void)in_sizes; (void)n_in; (void)out_size; (void)ws_size;

    char* ws = (char*)d_ws;
    size_t off = 0;
    int* row_ptr = (int*)(ws + off);
    off += (((size_t)(N_NODES + 1) * sizeof(int)) + 255) & ~(size_t)255;
    unsigned short* x_cat = (unsigned short*)(ws + off);
    off += (size_t)N_NODES * 192 * sizeof(short);
    unsigned char* sup8 = (unsigned char*)(ws + off);         // fp8: L1 [N][128]; reused L2 [N][64]
    off += (size_t)N_NODES * NHID;
    uint2* meta = (uint2*)(ws + off);   off += (size_t)N_EDGES * sizeof(uint2);
    unsigned short* w1t = (unsigned short*)(ws + off); off += (size_t)NHID * NFEAT * sizeof(short);
    unsigned short* w2t = (unsigned short*)(ws + off); off += (size_t)NHID2 * NHID * sizeof(short);
    unsigned short* wlt = (unsigned short*)(ws + off); off += (size_t)NCLS_P * 192 * sizeof(short);

    unsigned short* x1 = x_cat + NHID2;   // cols 64..191, stride 192
    unsigned short* x2 = x_cat;           // cols 0..63,   stride 192

    prep<<<(PREP_T4 + 255) / 256, 256, 0, stream>>>(edge_row, row_ptr, w1, w1t, w2, w2t, wl, wlt,
                                                    edge_col, edge_val, meta);

    // dynamic LDS sizes
    const int smem1 = 64 * 260 * 4;                               // 66560 (A panel, f32)
    const int smem2 = (128 + 64) * (NHID + 8) * 2;                // 52224
    const int smemH = (128 + 64) * (192 + 8) * 2 + 128 * 65 * 4 + NCLASS * 4;  // 110240

    // layer 1: sup8(fp8) = fp8(x @ w1); x1 = relu(spmm(sup8) + b1)
    gemm1_glds<<<dim3((N_NODES + 63) / 64, 1), 256, smem1, stream>>>(x, w1t, sup8, N_NODES);
    spmm_fp8<<<(N_NODES + 3) / 4, 256, 0, stream>>>(sup8, row_ptr, meta, b1, x1, 192, N_NODES);

    // layer 2: sup8(fp8,[N][64]) = fp8(x1 @ w2); x2 = relu(spmm2(sup8) + b2)
    gemm_full<NHID2, NHID, 2><<<dim3((N_NODES + 127) / 128, 1), 512, smem2, stream>>>(
        x1, w2t, sup8, N_NODES, 192, NHID2);
    spmm2_fp8<<<(N_NODES + 3) / 4, 256, 0, stream>>>(sup8, row_ptr, meta, b2, x2, 192, N_NODES);

    // fused head
    head_fused<<<dim3((N_NODES + 127) / 128, 1), 512, smemH, stream>>>(x_cat, wlt, bl, out, N_NODES);
}

// Round 19
// 135.169 us; speedup vs baseline: 1.0353x; 1.0353x over previous
//
#include <hip/hip_runtime.h>
#include <math.h>

#define N_NODES 100000
#define N_EDGES 1600000
#define NFEAT   256
#define NHID    128
#define NHID2   64
#define NCLASS  40
#define NCLS_P  64

typedef __attribute__((ext_vector_type(8))) short bf16x8;
typedef __attribute__((ext_vector_type(4))) float f32x4;
typedef __attribute__((ext_vector_type(2))) float f32x2;

static __device__ inline unsigned short f2bf(float f) {
    union { float f; unsigned u; } v; v.f = f;
    unsigned r = v.u + 0x7FFF + ((v.u >> 16) & 1);   // RNE
    return (unsigned short)(r >> 16);
}
static __device__ inline unsigned pkbf(float a, float b) {   // packed bf16x2
    return (unsigned)f2bf(a) | ((unsigned)f2bf(b) << 16);
}
static __device__ inline float bfl(unsigned u) {             // low bf16 -> f32
    union { unsigned u; float f; } v; v.u = u << 16; return v.f;
}
static __device__ inline float bfraw(unsigned u) {           // high bf16 -> f32 (low mantissa garbage)
    union { unsigned u; float f; } v; v.u = u; return v.f;
}

// ---- fp8 e4m3 pack/unpack: HW cvt if available, bitwise fallback ----------
#if __has_builtin(__builtin_amdgcn_cvt_pk_fp8_f32) && __has_builtin(__builtin_amdgcn_cvt_pk_f32_fp8)
#define FP8_HW 1
#else
#define FP8_HW 0
static __device__ inline unsigned f2fp8_sw(float f) {        // e4m3fn, RNE, FTZ below 2^-6
    union { float f; unsigned u; } v; v.f = f;
    unsigned s = (v.u >> 24) & 0x80u;
    int e = (int)((v.u >> 23) & 0xFF) - 120;                 // fp8 exp field
    unsigned m = v.u & 0x7FFFFFu;
    if (e < 1) return s;                                     // flush tiny to 0
    unsigned keep = m >> 20, rest = m & 0xFFFFFu;
    keep += (rest > 0x80000u) || (rest == 0x80000u && (keep & 1));
    if (keep == 8) { keep = 0; ++e; }
    if (e > 15) { e = 15; keep = 6; }                        // clamp to 448
    return s | ((unsigned)e << 3) | keep;
}
static __device__ inline float fp8f_sw(unsigned b) {
    unsigned e = (b >> 3) & 0xF;
    union { unsigned u; float f; } v;
    v.u = ((b & 0x80u) << 24) | ((e + 120) << 23) | ((b & 7u) << 20);
    return e ? v.f : 0.f;
}
#endif

static __device__ inline unsigned pack4_fp8(float a, float b, float c, float d) {
#if FP8_HW
    int r = __builtin_amdgcn_cvt_pk_fp8_f32(a, b, 0, false);
    r = __builtin_amdgcn_cvt_pk_fp8_f32(c, d, r, true);
    return (unsigned)r;
#else
    return f2fp8_sw(a) | (f2fp8_sw(b) << 8) | (f2fp8_sw(c) << 16) | (f2fp8_sw(d) << 24);
#endif
}
static __device__ inline void unpack4_fp8(unsigned g, f32x2& lo, f32x2& hi) {
#if FP8_HW
    lo = __builtin_amdgcn_cvt_pk_f32_fp8((int)g, false);
    hi = __builtin_amdgcn_cvt_pk_f32_fp8((int)g, true);
#else
    lo.x = fp8f_sw(g & 0xFF); lo.y = fp8f_sw((g >> 8) & 0xFF);
    hi.x = fp8f_sw((g >> 16) & 0xFF); hi.y = fp8f_sw(g >> 24);
#endif
}

// ---------------------------------------------------------------------------
// Merged prep: CSR row_ptr + 3 weight transposes + packed edge meta {col,val}.
// ---------------------------------------------------------------------------
#define PREP_T0 (N_NODES + 1)
#define PREP_T1 (PREP_T0 + NHID * NFEAT)
#define PREP_T2 (PREP_T1 + NHID2 * NHID)
#define PREP_T3 (PREP_T2 + NCLS_P * 192)
#define PREP_T4 (PREP_T3 + N_EDGES)
__global__ void prep(const int* __restrict__ er, int* __restrict__ row_ptr,
                     const float* __restrict__ w1, unsigned short* __restrict__ w1t,
                     const float* __restrict__ w2, unsigned short* __restrict__ w2t,
                     const float* __restrict__ wl, unsigned short* __restrict__ wlt,
                     const int* __restrict__ ec, const float* __restrict__ ev,
                     uint2* __restrict__ meta) {
    int idx = blockIdx.x * blockDim.x + threadIdx.x;
    if (idx < PREP_T0) {
        int lo = 0, hi = N_EDGES;
        while (lo < hi) { int mid = (lo + hi) >> 1; if (er[mid] < idx) lo = mid + 1; else hi = mid; }
        row_ptr[idx] = lo;
    } else if (idx < PREP_T1) {
        int i = idx - PREP_T0;          // w1t[n][k]: n<128, k<256
        int n = i >> 8, k = i & 255;
        w1t[i] = f2bf(w1[k * NHID + n]);
    } else if (idx < PREP_T2) {
        int i = idx - PREP_T1;          // w2t[n][k]: n<64, k<128
        int n = i >> 7, k = i & 127;
        w2t[i] = f2bf(w2[k * NHID2 + n]);
    } else if (idx < PREP_T3) {
        int i = idx - PREP_T2;          // wlt[n][k]: n<64 (pad>=40 -> 0), k<192
        int n = i / 192, k = i - n * 192;
        wlt[i] = (n < NCLASS) ? f2bf(wl[k * NCLASS + n]) : (unsigned short)0;
    } else if (idx < PREP_T4) {
        int i = idx - PREP_T3;
        uint2 m; m.x = (unsigned)ec[i];
        union { float f; unsigned u; } v; v.f = ev[i];
        m.y = v.u;
        meta[i] = m;
    }
}

// ---------------------------------------------------------------------------
// Layer-1 GEMM, B-in-registers: sup8 = fp8(x @ w1t^T).
// BM=64, 256 threads, A-only LDS 33.8KB, 4 blocks/CU target.
// ---------------------------------------------------------------------------
__global__ __launch_bounds__(256, 4) void gemm1_breg(const float* __restrict__ A,
                                                     const unsigned short* __restrict__ Bt,
                                                     unsigned char* __restrict__ C, int M) {
    const int K = 256, S = K + 8;
    extern __shared__ char smem[];
    unsigned short* As = (unsigned short*)smem;     // [64][264] bf16

    int tid = threadIdx.x;
    int lane = tid & 63, wc = tid >> 6;             // 4 waves = 4 col slices
    int row0 = blockIdx.x * 64;

    bf16x8 br[2][8];
    #pragma unroll
    for (int ni = 0; ni < 2; ++ni)
        #pragma unroll
        for (int t = 0; t < 8; ++t) {
            int n = wc * 32 + ni * 16 + (lane & 15);
            br[ni][t] = *(const bf16x8*)(Bt + (size_t)n * K + t * 32 + ((lane >> 4) << 3));
        }

    #pragma unroll
    for (int ch = 0; ch < 4; ++ch) {
        float4 av[4];
        #pragma unroll
        for (int i = 0; i < 4; ++i) {
            int s = tid + (ch * 4 + i) * 256;
            int m = s >> 6, c = (s & 63) * 4;
            int row = row0 + m;
            av[i] = (row < M) ? *(const float4*)(A + (size_t)row * K + c)
                              : float4{0.f, 0.f, 0.f, 0.f};
        }
        #pragma unroll
        for (int i = 0; i < 4; ++i) {
            int s = tid + (ch * 4 + i) * 256;
            int m = s >> 6, c = (s & 63) * 4;
            uint2 p; p.x = pkbf(av[i].x, av[i].y); p.y = pkbf(av[i].z, av[i].w);
            *(uint2*)&As[m * S + c] = p;
        }
    }
    __syncthreads();

    f32x4 acc[4][2];
    #pragma unroll
    for (int i = 0; i < 4; ++i)
        #pragma unroll
        for (int j = 0; j < 2; ++j) acc[i][j] = f32x4{0.f, 0.f, 0.f, 0.f};

    #pragma unroll
    for (int t = 0; t < 8; ++t) {
        bf16x8 af[4];
        #pragma unroll
        for (int mi = 0; mi < 4; ++mi)
            af[mi] = *(const bf16x8*)&As[(mi * 16 + (lane & 15)) * S + t * 32 + ((lane >> 4) << 3)];
        #pragma unroll
        for (int mi = 0; mi < 4; ++mi)
            #pragma unroll
            for (int ni = 0; ni < 2; ++ni)
                acc[mi][ni] = __builtin_amdgcn_mfma_f32_16x16x32_bf16(af[mi], br[ni][t], acc[mi][ni], 0, 0, 0);
    }

    __syncthreads();
    float* Lf = (float*)As; const int LS = 132;
    #pragma unroll
    for (int mi = 0; mi < 4; ++mi) {
        int rt = mi * 16 + ((lane >> 4) << 2);
        #pragma unroll
        for (int ni = 0; ni < 2; ++ni) {
            int ct = wc * 32 + ni * 16 + (lane & 15);
            #pragma unroll
            for (int r = 0; r < 4; ++r) Lf[(rt + r) * LS + ct] = acc[mi][ni][r];
        }
    }
    __syncthreads();
    int rl = tid >> 2, c0 = (tid & 3) * 32;
    int row = row0 + rl;
    if (row < M) {
        unsigned u[8];
        #pragma unroll
        for (int q = 0; q < 8; ++q) {
            f32x4 v = *(const f32x4*)&Lf[rl * LS + c0 + q * 4];
            u[q] = pack4_fp8(v[0], v[1], v[2], v[3]);
        }
        unsigned char* o = C + (size_t)row * 128 + c0;
        *(uint4*)o = uint4{u[0], u[1], u[2], u[3]};
        *(uint4*)(o + 16) = uint4{u[4], u[5], u[6], u[7]};
    }
}

// ---------------------------------------------------------------------------
// Single-phase full-K MFMA GEMM (layer 2): C = A @ Bt^T.
// CMODE 1: bf16 strided stores. CMODE 2 (BN=64): fp8 packed via LDS repack
// (Lf[128][68] f32 = 34816 B = exactly As size for K=128).
// ---------------------------------------------------------------------------
template <int BN, int K, int CMODE>
__global__ __launch_bounds__(512) void gemm_full(const unsigned short* __restrict__ A,
                                                 const unsigned short* __restrict__ Bt,
                                                 void* __restrict__ C,
                                                 int M, int lda, int ldc) {
    const int S   = K + 8;
    const int OCT = K / 8;
    const int WC  = (BN == 128) ? 4 : 2;
    const int MF  = (BN == 128) ? 4 : 2;
    const int NF  = 2;
    const int NT  = K / 32;

    extern __shared__ char smem[];
    unsigned short* As = (unsigned short*)smem;           // [128][S]
    unsigned short* Bs = As + 128 * S;                    // [BN][S]

    int tid = threadIdx.x;
    int lane = tid & 63, wid = tid >> 6;
    int wr = wid / WC, wc = wid % WC;
    int row0 = blockIdx.x * 128;

    {
        const int NI = 128 * OCT / 512;
        uint4 av[NI];
        #pragma unroll
        for (int i = 0; i < NI; ++i) {
            int s = tid + i * 512;
            int m = s / OCT, kk = (s - m * OCT) * 8;
            int row = row0 + m;
            av[i] = (row < M) ? *(const uint4*)(A + (size_t)row * lda + kk)
                              : uint4{0u, 0u, 0u, 0u};
        }
        #pragma unroll
        for (int i = 0; i < NI; ++i) {
            int s = tid + i * 512;
            int m = s / OCT, kk = (s - m * OCT) * 8;
            *(uint4*)&As[m * S + kk] = av[i];
        }
    }
    {
        const int NI = BN * OCT / 512;
        uint4 bv[NI];
        #pragma unroll
        for (int i = 0; i < NI; ++i) {
            int s = tid + i * 512;
            int n = s / OCT, kk = (s - n * OCT) * 8;
            bv[i] = *(const uint4*)(Bt + (size_t)n * K + kk);
        }
        #pragma unroll
        for (int i = 0; i < NI; ++i) {
            int s = tid + i * 512;
            int n = s / OCT, kk = (s - n * OCT) * 8;
            *(uint4*)&Bs[n * S + kk] = bv[i];
        }
    }
    __syncthreads();

    f32x4 acc[MF][NF];
    #pragma unroll
    for (int i = 0; i < MF; ++i)
        #pragma unroll
        for (int j = 0; j < NF; ++j) acc[i][j] = f32x4{0.f, 0.f, 0.f, 0.f};

    #pragma unroll
    for (int t = 0; t < NT; ++t) {
        bf16x8 af[MF], bfr[NF];
        #pragma unroll
        for (int mi = 0; mi < MF; ++mi)
            af[mi] = *(const bf16x8*)&As[(wr * (MF * 16) + mi * 16 + (lane & 15)) * S + t * 32 + (lane >> 4) * 8];
        #pragma unroll
        for (int ni = 0; ni < NF; ++ni)
            bfr[ni] = *(const bf16x8*)&Bs[(wc * (NF * 16) + ni * 16 + (lane & 15)) * S + t * 32 + (lane >> 4) * 8];
        #pragma unroll
        for (int mi = 0; mi < MF; ++mi)
            #pragma unroll
            for (int ni = 0; ni < NF; ++ni)
                acc[mi][ni] = __builtin_amdgcn_mfma_f32_16x16x32_bf16(af[mi], bfr[ni], acc[mi][ni], 0, 0, 0);
    }

    if (CMODE == 1) {
        #pragma unroll
        for (int mi = 0; mi < MF; ++mi) {
            int rbase = row0 + wr * (MF * 16) + mi * 16 + ((lane >> 4) << 2);
            #pragma unroll
            for (int ni = 0; ni < NF; ++ni) {
                int col = wc * (NF * 16) + ni * 16 + (lane & 15);
                #pragma unroll
                for (int r = 0; r < 4; ++r) {
                    int row = rbase + r;
                    if (row < M) ((unsigned short*)C)[(size_t)row * ldc + col] = f2bf(acc[mi][ni][r]);
                }
            }
        }
    } else {
        // fp8 packed (BN=64): acc -> f32 LDS (reuse As) -> 16B/thread stores
        __syncthreads();
        float* Lf = (float*)As; const int LS = BN + 4;         // 68
        #pragma unroll
        for (int mi = 0; mi < MF; ++mi) {
            int rt = wr * (MF * 16) + mi * 16 + ((lane >> 4) << 2);
            #pragma unroll
            for (int ni = 0; ni < NF; ++ni) {
                int ct = wc * (NF * 16) + ni * 16 + (lane & 15);
                #pragma unroll
                for (int r = 0; r < 4; ++r) Lf[(rt + r) * LS + ct] = acc[mi][ni][r];
            }
        }
        __syncthreads();
        int rl = tid >> 2, c0 = (tid & 3) * 16;                // 4 thr/row, 16 fp8 each
        int row = row0 + rl;
        if (row < M) {
            unsigned u[4];
            #pragma unroll
            for (int q = 0; q < 4; ++q) {
                f32x4 v = *(const f32x4*)&Lf[rl * LS + c0 + q * 4];
                u[q] = pack4_fp8(v[0], v[1], v[2], v[3]);
            }
            *(uint4*)((unsigned char*)C + (size_t)row * BN + c0) = uint4{u[0], u[1], u[2], u[3]};
        }
    }
}

// ---------------------------------------------------------------------------
// Layer-1 SpMM over fp8 sup8[node][128] (128B/row) + bias + relu -> bf16 out.
// ---------------------------------------------------------------------------
__global__ __launch_bounds__(256) void spmm_fp8(const unsigned char* __restrict__ sup8,
                                                const int* __restrict__ row_ptr,
                                                const uint2* __restrict__ meta,
                                                const float* __restrict__ bias,
                                                unsigned short* __restrict__ out,
                                                int out_stride, int n_nodes) {
    __shared__ uint2 mlds[4][64];

    int wave = threadIdx.x >> 6;
    int lane = threadIdx.x & 63;
    int node = blockIdx.x * 4 + wave;
    if (node >= n_nodes) return;

    int sub = lane >> 5, l = lane & 31;
    int e0 = row_ptr[node];
    int cnt = row_ptr[node + 1] - e0;
    unsigned loff = (unsigned)(l << 2);

    f32x2 a0 = {0.f, 0.f}, a1 = {0.f, 0.f};

    for (int o = 0; o < cnt; o += 64) {
        int rem = min(64, cnt - o);
        uint2 m;
        if (lane < rem) m = meta[e0 + o + lane];
        else { m.x = 0u; m.y = 0u; }
        mlds[wave][lane] = m;

        for (int j = 0; j < rem; j += 16) {
            unsigned g[8]; float vv[8];
            #pragma unroll
            for (int t = 0; t < 8; ++t) {
                uint2 cm = mlds[wave][j + 2 * t + sub];
                g[t] = *(const unsigned*)(sup8 + (((size_t)cm.x) << 7) + loff);
                union { unsigned u; float f; } c; c.u = cm.y;
                vv[t] = c.f;
            }
            #pragma unroll
            for (int t = 0; t < 8; ++t) {
                f32x2 lo, hi;
                unpack4_fp8(g[t], lo, hi);
                f32x2 v2 = {vv[t], vv[t]};
                a0 += v2 * lo;
                a1 += v2 * hi;
            }
        }
    }

    a0.x += __shfl_xor(a0.x, 32); a0.y += __shfl_xor(a0.y, 32);
    a1.x += __shfl_xor(a1.x, 32); a1.y += __shfl_xor(a1.y, 32);

    if (lane < 32) {
        float4 bv = *(const float4*)(bias + 4 * l);
        float r0 = a0.x + bv.x, r1 = a0.y + bv.y;
        float r2 = a1.x + bv.z, r3 = a1.y + bv.w;
        r0 = r0 > 0.f ? r0 : 0.f; r1 = r1 > 0.f ? r1 : 0.f;
        r2 = r2 > 0.f ? r2 : 0.f; r3 = r3 > 0.f ? r3 : 0.f;
        uint2 pk; pk.x = pkbf(r0, r1); pk.y = pkbf(r2, r3);
        *(uint2*)(out + (size_t)node * out_stride + 4 * l) = pk;
    }
}

// ---------------------------------------------------------------------------
// Layer-2 SpMM over fp8 sup8_2[node][64] (64B/row) + bias + relu -> bf16 out.
// Quarter-wave (16 lanes x 4B = 64B) per edge; 8 gathers (32 edges) in flight.
// Lane l owns channels 4l..4l+3.
// ---------------------------------------------------------------------------
__global__ __launch_bounds__(256) void spmm2_fp8(const unsigned char* __restrict__ sup8,
                                                 const int* __restrict__ row_ptr,
                                                 const uint2* __restrict__ meta,
                                                 const float* __restrict__ bias,
                                                 unsigned short* __restrict__ out,
                                                 int out_stride, int n_nodes) {
    __shared__ uint2 mlds[4][64];

    int wave = threadIdx.x >> 6;
    int lane = threadIdx.x & 63;
    int node = blockIdx.x * 4 + wave;
    if (node >= n_nodes) return;

    int sub = lane >> 4, l = lane & 15;
    int e0 = row_ptr[node];
    int cnt = row_ptr[node + 1] - e0;
    unsigned loff = (unsigned)(l << 2);

    f32x2 a0 = {0.f, 0.f}, a1 = {0.f, 0.f};

    for (int o = 0; o < cnt; o += 64) {
        int rem = min(64, cnt - o);
        uint2 m;
        if (lane < rem) m = meta[e0 + o + lane];
        else { m.x = 0u; m.y = 0u; }
        mlds[wave][lane] = m;

        for (int j = 0; j < rem; j += 32) {
            unsigned g[8]; float vv[8];
            #pragma unroll
            for (int t = 0; t < 8; ++t) {
                uint2 cm = mlds[wave][j + 4 * t + sub];
                g[t] = *(const unsigned*)(sup8 + (((size_t)cm.x) << 6) + loff);
                union { unsigned u; float f; } c; c.u = cm.y;
                vv[t] = c.f;
            }
            #pragma unroll
            for (int t = 0; t < 8; ++t) {
                f32x2 lo, hi;
                unpack4_fp8(g[t], lo, hi);
                f32x2 v2 = {vv[t], vv[t]};
                a0 += v2 * lo;
                a1 += v2 * hi;
            }
        }
    }

    a0.x += __shfl_xor(a0.x, 32); a0.y += __shfl_xor(a0.y, 32);
    a1.x += __shfl_xor(a1.x, 32); a1.y += __shfl_xor(a1.y, 32);
    a0.x += __shfl_xor(a0.x, 16); a0.y += __shfl_xor(a0.y, 16);
    a1.x += __shfl_xor(a1.x, 16); a1.y += __shfl_xor(a1.y, 16);

    if (lane < 16) {
        float4 bv = *(const float4*)(bias + 4 * l);
        float r0 = a0.x + bv.x, r1 = a0.y + bv.y;
        float r2 = a1.x + bv.z, r3 = a1.y + bv.w;
        r0 = r0 > 0.f ? r0 : 0.f; r1 = r1 > 0.f ? r1 : 0.f;
        r2 = r2 > 0.f ? r2 : 0.f; r3 = r3 > 0.f ? r3 : 0.f;
        uint2 pk; pk.x = pkbf(r0, r1); pk.y = pkbf(r2, r3);
        *(uint2*)(out + (size_t)node * out_stride + 4 * l) = pk;
    }
}

// ---------------------------------------------------------------------------
// Fused head: out = log_softmax(x_cat[M,192](bf16) @ wlt[64,192]^T + bl).
// ---------------------------------------------------------------------------
__global__ __launch_bounds__(512) void head_fused(const unsigned short* __restrict__ A,
                                                  const unsigned short* __restrict__ Bt,
                                                  const float* __restrict__ bl,
                                                  float* __restrict__ out, int M) {
    const int K = 192, S = K + 8, OCT = K / 8;   // 24
    const int MF = 2, NF = 2, NT = 6;

    extern __shared__ char smem[];
    unsigned short* As = (unsigned short*)smem;        // [128][200]
    unsigned short* Bs = As + 128 * S;                 // [64][200]
    float* L  = (float*)(Bs + 64 * S);                 // [128][65]
    float* bls = L + 128 * 65;                         // [40]

    int tid = threadIdx.x;
    int lane = tid & 63, wid = tid >> 6;
    int wr = wid >> 1, wc = wid & 1;
    int row0 = blockIdx.x * 128;
    if (tid < NCLASS) bls[tid] = bl[tid];

    {
        uint4 av[6];
        #pragma unroll
        for (int i = 0; i < 6; ++i) {
            int s = tid + i * 512;
            int m = s / OCT, kk = (s - m * OCT) * 8;
            int row = row0 + m;
            av[i] = (row < M) ? *(const uint4*)(A + (size_t)row * 192 + kk)
                              : uint4{0u, 0u, 0u, 0u};
        }
        #pragma unroll
        for (int i = 0; i < 6; ++i) {
            int s = tid + i * 512;
            int m = s / OCT, kk = (s - m * OCT) * 8;
            *(uint4*)&As[m * S + kk] = av[i];
        }
    }
    {
        uint4 bv[3];
        #pragma unroll
        for (int i = 0; i < 3; ++i) {
            int s = tid + i * 512;
            int n = s / OCT, kk = (s - n * OCT) * 8;
            bv[i] = *(const uint4*)(Bt + (size_t)n * 192 + kk);
        }
        #pragma unroll
        for (int i = 0; i < 3; ++i) {
            int s = tid + i * 512;
            int n = s / OCT, kk = (s - n * OCT) * 8;
            *(uint4*)&Bs[n * S + kk] = bv[i];
        }
    }
    __syncthreads();

    f32x4 acc[MF][NF];
    #pragma unroll
    for (int i = 0; i < MF; ++i)
        #pragma unroll
        for (int j = 0; j < NF; ++j) acc[i][j] = f32x4{0.f, 0.f, 0.f, 0.f};

    #pragma unroll
    for (int t = 0; t < NT; ++t) {
        bf16x8 af[MF], bfr[NF];
        #pragma unroll
        for (int mi = 0; mi < MF; ++mi)
            af[mi] = *(const bf16x8*)&As[(wr * 32 + mi * 16 + (lane & 15)) * S + t * 32 + (lane >> 4) * 8];
        #pragma unroll
        for (int ni = 0; ni < NF; ++ni)
            bfr[ni] = *(const bf16x8*)&Bs[(wc * 32 + ni * 16 + (lane & 15)) * S + t * 32 + (lane >> 4) * 8];
        #pragma unroll
        for (int mi = 0; mi < MF; ++mi)
            #pragma unroll
            for (int ni = 0; ni < NF; ++ni)
                acc[mi][ni] = __builtin_amdgcn_mfma_f32_16x16x32_bf16(af[mi], bfr[ni], acc[mi][ni], 0, 0, 0);
    }

    #pragma unroll
    for (int mi = 0; mi < MF; ++mi) {
        int rt = wr * 32 + mi * 16 + ((lane >> 4) << 2);
        #pragma unroll
        for (int ni = 0; ni < NF; ++ni) {
            int ct = wc * 32 + ni * 16 + (lane & 15);
            #pragma unroll
            for (int r = 0; r < 4; ++r) L[(rt + r) * 65 + ct] = acc[mi][ni][r];
        }
    }
    __syncthreads();

    {
        int r = tid >> 2, h = tid & 3;
        int row = row0 + r;
        if (row < M) {
            float vals[10];
            float m = -1e30f;
            #pragma unroll
            for (int c = 0; c < 10; ++c) {
                float tv = L[r * 65 + h * 10 + c] + bls[h * 10 + c];
                vals[c] = tv;
                m = fmaxf(m, tv);
            }
            m = fmaxf(m, __shfl_xor(m, 1));
            m = fmaxf(m, __shfl_xor(m, 2));
            float s = 0.f;
            #pragma unroll
            for (int c = 0; c < 10; ++c) s += __expf(vals[c] - m);
            s += __shfl_xor(s, 1);
            s += __shfl_xor(s, 2);
            float lg = __logf(s);
            float* o = out + (size_t)row * NCLASS + h * 10;
            #pragma unroll
            for (int c = 0; c < 10; ++c) o[c] = vals[c] - m - lg;
        }
    }
}

// ---------------------------------------------------------------------------
extern "C" void kernel_launch(void* const* d_in, const int* in_sizes, int n_in,
                              void* d_out, int out_size, void* d_ws, size_t ws_size,
                              hipStream_t stream) {
    const float* x        = (const float*)d_in[0];
    const int*   edge_row = (const int*)d_in[1];
    const int*   edge_col = (const int*)d_in[2];
    const float* edge_val = (const float*)d_in[3];
    const float* w1       = (const float*)d_in[4];
    const float* b1       = (const float*)d_in[5];
    const float* w2       = (const float*)d_in[6];
    const float* b2       = (const float*)d_in[7];
    const float* wl       = (const float*)d_in[8];
    const float* bl       = (const float*)d_in[9];
    float* out = (float*)d_out;
    (void)in_sizes; (void)n_in; (void)out_size; (void)ws_size;

    char* ws = (char*)d_ws;
    size_t off = 0;
    int* row_ptr = (int*)(ws + off);
    off += (((size_t)(N_NODES + 1) * sizeof(int)) + 255) & ~(size_t)255;
    unsigned short* x_cat = (unsigned short*)(ws + off);
    off += (size_t)N_NODES * 192 * sizeof(short);
    unsigned char* sup8 = (unsigned char*)(ws + off);         // fp8: L1 [N][128]; reused L2 [N][64]
    off += (size_t)N_NODES * NHID;
    uint2* meta = (uint2*)(ws + off);   off += (size_t)N_EDGES * sizeof(uint2);
    unsigned short* w1t = (unsigned short*)(ws + off); off += (size_t)NHID * NFEAT * sizeof(short);
    unsigned short* w2t = (unsigned short*)(ws + off); off += (size_t)NHID2 * NHID * sizeof(short);
    unsigned short* wlt = (unsigned short*)(ws + off); off += (size_t)NCLS_P * 192 * sizeof(short);

    unsigned short* x1 = x_cat + NHID2;   // cols 64..191, stride 192
    unsigned short* x2 = x_cat;           // cols 0..63,   stride 192

    prep<<<(PREP_T4 + 255) / 256, 256, 0, stream>>>(edge_row, row_ptr, w1, w1t, w2, w2t, wl, wlt,
                                                    edge_col, edge_val, meta);

    // dynamic LDS sizes
    const int smem1 = 64 * (NFEAT + 8) * 2;                       // 33792 (A panel only)
    const int smem2 = (128 + 64) * (NHID + 8) * 2;                // 52224
    const int smemH = (128 + 64) * (192 + 8) * 2 + 128 * 65 * 4 + NCLASS * 4;  // 110240

    // layer 1: sup8(fp8) = fp8(x @ w1); x1 = relu(spmm(sup8) + b1)
    gemm1_breg<<<dim3((N_NODES + 63) / 64, 1), 256, smem1, stream>>>(x, w1t, sup8, N_NODES);
    spmm_fp8<<<(N_NODES + 3) / 4, 256, 0, stream>>>(sup8, row_ptr, meta, b1, x1, 192, N_NODES);

    // layer 2: sup8(fp8,[N][64]) = fp8(x1 @ w2); x2 = relu(spmm2(sup8) + b2)
    gemm_full<NHID2, NHID, 2><<<dim3((N_NODES + 127) / 128, 1), 512, smem2, stream>>>(
        x1, w2t, sup8, N_NODES, 192, NHID2);
    spmm2_fp8<<<(N_NODES + 3) / 4, 256, 0, stream>>>(sup8, row_ptr, meta, b2, x2, 192, N_NODES);

    // fused head
    head_fused<<<dim3((N_NODES + 127) / 128, 1), 512, smemH, stream>>>(x_cat, wlt, bl, out, N_NODES);
}